// Round 9
// baseline (469.669 us; speedup 1.0000x reference)
//
#include <hip/hip_runtime.h>

#define NN 20000
#define NE 320000
#define BH 768
#define GH 256

typedef __attribute__((ext_vector_type(8))) short short8;
typedef __attribute__((ext_vector_type(4))) float f32x4;

// ---------------- bf16 helpers (RNE) ----------------
__device__ __forceinline__ ushort f2bf(float x) {
    union { float f; unsigned u; } v; v.f = x;
    unsigned r = (v.u + 0x7FFFu + ((v.u >> 16) & 1u)) >> 16;
    return (ushort)r;
}
__device__ __forceinline__ float bf2f(ushort h) {
    union { unsigned u; float f; } v; v.u = ((unsigned)h) << 16;
    return v.f;
}

__device__ __forceinline__ void gload_lds16(const void* g, void* l) {
    __builtin_amdgcn_global_load_lds(
        (const __attribute__((address_space(1))) void*)g,
        (__attribute__((address_space(3))) void*)l, 16, 0, 0);
}

// ---------------- CSR build ----------------

__global__ void k_count(const int* __restrict__ dst, int* __restrict__ cnt, int E) {
    int i = blockIdx.x * blockDim.x + threadIdx.x;
    if (i < E) atomicAdd(&cnt[dst[i]], 1);
}

// chunked single-block scan: 1024 threads x 20 contiguous elements each.
__global__ __launch_bounds__(1024)
void k_scan(const int* __restrict__ cnt, int* __restrict__ off,
            int* __restrict__ fill, int n) {
    __shared__ int sbuf[1024];
    const int tid  = threadIdx.x;
    const int base = tid * 20;
    int local[20];
    int s = 0;
    #pragma unroll
    for (int i = 0; i < 20; ++i) {
        const int idx = base + i;
        int v = (idx < n) ? cnt[idx] : 0;
        local[i] = s;            // exclusive-within-chunk
        s += v;
    }
    sbuf[tid] = s;
    __syncthreads();
    int sum = s;
    for (int ofs = 1; ofs < 1024; ofs <<= 1) {
        int other = (tid >= ofs) ? sbuf[tid - ofs] : 0;
        __syncthreads();
        sum += other;
        sbuf[tid] = sum;
        __syncthreads();
    }
    const int excl = sum - s;    // exclusive prefix of this chunk
    #pragma unroll
    for (int i = 0; i < 20; ++i) {
        const int idx = base + i;
        if (idx < n) { const int v = excl + local[i]; off[idx] = v; fill[idx] = v; }
    }
    if (tid == 1023) off[n] = sum;
}

__global__ void k_scatter(const int* __restrict__ src, const int* __restrict__ dst,
                          const float* __restrict__ w, int* __restrict__ fill,
                          int* __restrict__ csr_src, float* __restrict__ csr_w, int E) {
    int i = blockIdx.x * blockDim.x + threadIdx.x;
    if (i < E) {
        int d = dst[i];
        int p = atomicAdd(&fill[d], 1);
        csr_src[p] = src[i];
        csr_w[p]  = w[i];
    }
}

// ---------------- fp32 -> bf16 hi/lo split (elementwise, float4) ----------------

__global__ void k_split(const float* __restrict__ x, ushort* __restrict__ hi,
                        ushort* __restrict__ lo, int n4) {
    int i = blockIdx.x * blockDim.x + threadIdx.x;
    if (i >= n4) return;
    float4 v = ((const float4*)x)[i];
    ushort4 h, l;
    h.x = f2bf(v.x); l.x = f2bf(v.x - bf2f(h.x));
    h.y = f2bf(v.y); l.y = f2bf(v.y - bf2f(h.y));
    h.z = f2bf(v.z); l.z = f2bf(v.z - bf2f(h.z));
    h.w = f2bf(v.w); l.w = f2bf(v.w - bf2f(h.w));
    ((ushort4*)hi)[i] = h;
    ((ushort4*)lo)[i] = l;
}

// W[K][N] row-major -> hi/lo planes transposed to [N][K]
__global__ void k_splitw(const float* __restrict__ W, ushort* __restrict__ hi,
                         ushort* __restrict__ lo, int K, int N) {
    int id = blockIdx.x * blockDim.x + threadIdx.x;
    if (id >= K * N) return;
    int n = id / K, k = id % K;
    float v = W[(size_t)k * N + n];
    ushort h = f2bf(v);
    hi[id] = h;
    lo[id] = f2bf(v - bf2f(h));
}

// ---------------- bf16x3 MFMA GEMM ----------------
// C[M x 256] = (Ah+Al)[M x K] * (Bh+Bl)^T  where B planes are stored [256][K].
// Tile BM=64, BN=64, BK=32; 256 threads = 4 waves (2m x 2n), wave-tile 32x32.
// Grid (4, ceil(M/64)) = 1252 blocks (~4.9/CU) so co-resident blocks hide the
// 2-barrier staging drain (round-5: 626 blocks -> Occupancy 18%, MfmaUtil 18%).
// LDS tiles [rows][32] bf16, slot-swizzled: phys_slot = slot ^ ((row>>1)&3)
// (applied on the global source so global_load_lds stays linear; undone on read).

__global__ __launch_bounds__(256)
void k_gemm_mfma(const ushort* __restrict__ Ah, const ushort* __restrict__ Al,
                 int lda, int K,
                 const ushort* __restrict__ Bh, const ushort* __restrict__ Bl,
                 const float* __restrict__ bias,
                 float* __restrict__ C, int M) {
    __shared__ ushort As_h[64 * 32];
    __shared__ ushort As_l[64 * 32];
    __shared__ ushort Bs_h[64 * 32];
    __shared__ ushort Bs_l[64 * 32];

    const int t    = threadIdx.x;
    const int lane = t & 63;
    const int m0   = blockIdx.y * 64;
    const int n0   = blockIdx.x * 64;

    // staging: 64 rows x 4 slots = 256 chunks of 16B, one per thread (per plane)
    const int ra = t >> 2;
    const int sa = (t & 3) ^ ((ra >> 1) & 3);
    int rga = m0 + ra; if (rga > M - 1) rga = M - 1;
    const size_t aofs = (size_t)rga * lda + (size_t)(sa * 8);
    const size_t bofs = (size_t)(n0 + ra) * K + (size_t)(sa * 8);
    const int dofs = (t >> 6) << 10;   // wave-contiguous 1KB LDS region
    char* a_dst_h = (char*)As_h + dofs;
    char* a_dst_l = (char*)As_l + dofs;
    char* b_dst_h = (char*)Bs_h + dofs;
    char* b_dst_l = (char*)Bs_l + dofs;

    const int wm = (t >> 6) & 1;
    const int wn = t >> 7;

    f32x4 zero = (f32x4)0.0f;
    f32x4 acc[2][2];
    #pragma unroll
    for (int i = 0; i < 2; ++i)
        #pragma unroll
        for (int j = 0; j < 2; ++j) acc[i][j] = zero;

    const int fr  = lane & 15;
    const int fsl = lane >> 4;

    for (int k0 = 0; k0 < K; k0 += 32) {
        __syncthreads();
        gload_lds16(Ah + aofs + k0, a_dst_h);
        gload_lds16(Al + aofs + k0, a_dst_l);
        gload_lds16(Bh + bofs + k0, b_dst_h);
        gload_lds16(Bl + bofs + k0, b_dst_l);
        __syncthreads();

        short8 ah[2], al2[2], bh[2], bl[2];
        #pragma unroll
        for (int i = 0; i < 2; ++i) {
            const int r = wm * 32 + i * 16 + fr;
            const int s = fsl ^ ((r >> 1) & 3);
            ah[i]  = *(const short8*)(As_h + r * 32 + s * 8);
            al2[i] = *(const short8*)(As_l + r * 32 + s * 8);
        }
        #pragma unroll
        for (int j = 0; j < 2; ++j) {
            const int r = wn * 32 + j * 16 + fr;
            const int s = fsl ^ ((r >> 1) & 3);
            bh[j] = *(const short8*)(Bs_h + r * 32 + s * 8);
            bl[j] = *(const short8*)(Bs_l + r * 32 + s * 8);
        }
        #pragma unroll
        for (int i = 0; i < 2; ++i)
            #pragma unroll
            for (int j = 0; j < 2; ++j) {
                acc[i][j] = __builtin_amdgcn_mfma_f32_16x16x32_bf16(ah[i],  bh[j], acc[i][j], 0, 0, 0);
                acc[i][j] = __builtin_amdgcn_mfma_f32_16x16x32_bf16(ah[i],  bl[j], acc[i][j], 0, 0, 0);
                acc[i][j] = __builtin_amdgcn_mfma_f32_16x16x32_bf16(al2[i], bh[j], acc[i][j], 0, 0, 0);
            }
    }

    // epilogue: C/D layout col = lane&15, row = (lane>>4)*4 + reg
    #pragma unroll
    for (int i = 0; i < 2; ++i) {
        #pragma unroll
        for (int j = 0; j < 2; ++j) {
            const int col = n0 + wn * 32 + j * 16 + fr;
            const int r0  = m0 + wm * 32 + i * 16 + ((lane >> 4) << 2);
            const float ba = bias ? bias[col] : 0.0f;
            #pragma unroll
            for (int q = 0; q < 4; ++q) {
                const int r = r0 + q;
                if (r < M) C[(size_t)r * 256 + col] = acc[i][j][q] + ba;
            }
        }
    }
}

// ---------------- edge aggregation + bias + relu -> bf16 hi/lo concat planes --------
// one wave per node; lane owns 4 contiguous floats of the 256-dim feature.
// 4-way edge unroll: 4 independent accumulators -> 4 gathers in flight per wave.

__global__ __launch_bounds__(256)
void k_aggregate(const float* __restrict__ y,
                 const int* __restrict__ off,
                 const int* __restrict__ csr_src,
                 const float* __restrict__ csr_w,
                 const float* __restrict__ bias,
                 ushort* __restrict__ cat_h,   // plane + layer*256; row stride 768
                 ushort* __restrict__ cat_l,
                 int n) {
    const int wave = blockIdx.x * (blockDim.x >> 6) + (threadIdx.x >> 6);
    const int lane = threadIdx.x & 63;
    if (wave >= n) return;
    const int c = lane * 4;

    // independent (hoisted) loads: overlap with the edge loop
    float4 self = *(const float4*)(y + (size_t)wave * GH + c);
    float4 b    = *(const float4*)(bias + c);

    float4 a0 = make_float4(0.f, 0.f, 0.f, 0.f);
    float4 a1 = a0, a2 = a0, a3 = a0;
    const int e0 = off[wave], e1 = off[wave + 1];
    int e = e0;
    for (; e + 4 <= e1; e += 4) {
        const int   s0 = csr_src[e],     s1 = csr_src[e + 1];
        const int   s2 = csr_src[e + 2], s3 = csr_src[e + 3];
        const float w0 = csr_w[e],       w1 = csr_w[e + 1];
        const float w2 = csr_w[e + 2],   w3 = csr_w[e + 3];
        float4 v0 = *(const float4*)(y + (size_t)s0 * GH + c);
        float4 v1 = *(const float4*)(y + (size_t)s1 * GH + c);
        float4 v2 = *(const float4*)(y + (size_t)s2 * GH + c);
        float4 v3 = *(const float4*)(y + (size_t)s3 * GH + c);
        a0.x = fmaf(w0, v0.x, a0.x); a0.y = fmaf(w0, v0.y, a0.y);
        a0.z = fmaf(w0, v0.z, a0.z); a0.w = fmaf(w0, v0.w, a0.w);
        a1.x = fmaf(w1, v1.x, a1.x); a1.y = fmaf(w1, v1.y, a1.y);
        a1.z = fmaf(w1, v1.z, a1.z); a1.w = fmaf(w1, v1.w, a1.w);
        a2.x = fmaf(w2, v2.x, a2.x); a2.y = fmaf(w2, v2.y, a2.y);
        a2.z = fmaf(w2, v2.z, a2.z); a2.w = fmaf(w2, v2.w, a2.w);
        a3.x = fmaf(w3, v3.x, a3.x); a3.y = fmaf(w3, v3.y, a3.y);
        a3.z = fmaf(w3, v3.z, a3.z); a3.w = fmaf(w3, v3.w, a3.w);
    }
    for (; e < e1; ++e) {
        const int   s = csr_src[e];
        const float w = csr_w[e];
        float4 v = *(const float4*)(y + (size_t)s * GH + c);
        a0.x = fmaf(w, v.x, a0.x); a0.y = fmaf(w, v.y, a0.y);
        a0.z = fmaf(w, v.z, a0.z); a0.w = fmaf(w, v.w, a0.w);
    }
    float4 r;
    r.x = fmaxf(self.x + ((a0.x + a1.x) + (a2.x + a3.x)) + b.x, 0.f);
    r.y = fmaxf(self.y + ((a0.y + a1.y) + (a2.y + a3.y)) + b.y, 0.f);
    r.z = fmaxf(self.z + ((a0.z + a1.z) + (a2.z + a3.z)) + b.z, 0.f);
    r.w = fmaxf(self.w + ((a0.w + a1.w) + (a2.w + a3.w)) + b.w, 0.f);
    ushort4 h, l;
    h.x = f2bf(r.x); l.x = f2bf(r.x - bf2f(h.x));
    h.y = f2bf(r.y); l.y = f2bf(r.y - bf2f(h.y));
    h.z = f2bf(r.z); l.z = f2bf(r.z - bf2f(h.z));
    h.w = f2bf(r.w); l.w = f2bf(r.w - bf2f(h.w));
    *(ushort4*)(cat_h + (size_t)wave * BH + c) = h;
    *(ushort4*)(cat_l + (size_t)wave * BH + c) = l;
}

// ---------------- launcher ----------------

extern "C" void kernel_launch(void* const* d_in, const int* in_sizes, int n_in,
                              void* d_out, int out_size, void* d_ws, size_t ws_size,
                              hipStream_t stream) {
    const float* node_embed = (const float*)d_in[0];
    const float* edge_w     = (const float*)d_in[1];
    const float* W0 = (const float*)d_in[2];
    const float* b0 = (const float*)d_in[3];
    const float* W1 = (const float*)d_in[4];
    const float* b1 = (const float*)d_in[5];
    const float* W2 = (const float*)d_in[6];
    const float* b2 = (const float*)d_in[7];
    const float* Wr = (const float*)d_in[8];
    const float* br = (const float*)d_in[9];
    const int* src  = (const int*)d_in[10];
    const int* dst  = (const int*)d_in[11];
    float* out = (float*)d_out;

    char* p = (char*)d_ws;
    auto carve = [&](size_t bytes) {
        void* r = (void*)p;
        p += (bytes + 255) & ~(size_t)255;
        return r;
    };
    ushort* plane_h = (ushort*)carve((size_t)NN * BH * 2);   // 30.72 MB
    ushort* plane_l = (ushort*)carve((size_t)NN * BH * 2);   // 30.72 MB
    float*  y       = (float*) carve((size_t)NN * GH * 4);   // 20.48 MB
    ushort* wt0_h = (ushort*)carve((size_t)GH * BH * 2);
    ushort* wt0_l = (ushort*)carve((size_t)GH * BH * 2);
    ushort* wt1_h = (ushort*)carve((size_t)GH * GH * 2);
    ushort* wt1_l = (ushort*)carve((size_t)GH * GH * 2);
    ushort* wt2_h = (ushort*)carve((size_t)GH * GH * 2);
    ushort* wt2_l = (ushort*)carve((size_t)GH * GH * 2);
    ushort* wtr_h = (ushort*)carve((size_t)GH * BH * 2);
    ushort* wtr_l = (ushort*)carve((size_t)GH * BH * 2);
    int*    cnt     = (int*)  carve((size_t)NN * 4);
    int*    off     = (int*)  carve((size_t)(NN + 1) * 4);
    int*    fill    = (int*)  carve((size_t)NN * 4);
    int*    csr_src = (int*)  carve((size_t)NE * 4);
    float*  csr_w   = (float*)carve((size_t)NE * 4);
    (void)ws_size; (void)n_in; (void)in_sizes; (void)out_size;

    // --- CSR build ---
    hipMemsetAsync(cnt, 0, (size_t)NN * 4, stream);
    k_count<<<(NE + 255) / 256, 256, 0, stream>>>(dst, cnt, NE);
    k_scan<<<1, 1024, 0, stream>>>(cnt, off, fill, NN);
    k_scatter<<<(NE + 255) / 256, 256, 0, stream>>>(src, dst, edge_w, fill,
                                                    csr_src, csr_w, NE);

    // --- precision splits ---
    const int n4 = NN * BH / 4;
    k_split<<<(n4 + 255) / 256, 256, 0, stream>>>(node_embed, plane_h, plane_l, n4);
    k_splitw<<<(BH * GH + 255) / 256, 256, 0, stream>>>(W0, wt0_h, wt0_l, BH, GH);
    k_splitw<<<(GH * GH + 255) / 256, 256, 0, stream>>>(W1, wt1_h, wt1_l, GH, GH);
    k_splitw<<<(GH * GH + 255) / 256, 256, 0, stream>>>(W2, wt2_h, wt2_l, GH, GH);
    k_splitw<<<(BH * GH + 255) / 256, 256, 0, stream>>>(Wr, wtr_h, wtr_l, BH, GH);

    dim3 gemm_grid(4, (NN + 63) / 64);          // (4, 313) = 1252 blocks
    const int agg_blocks = (NN + 3) / 4;        // 4 waves/block, 1 node/wave

    // --- layer 0: project first (768->256), then aggregate in 256-dim ---
    k_gemm_mfma<<<gemm_grid, 256, 0, stream>>>(plane_h, plane_l, BH, BH,
                                               wt0_h, wt0_l, nullptr, y, NN);
    k_aggregate<<<agg_blocks, 256, 0, stream>>>(y, off, csr_src, csr_w, b0,
                                                plane_h + 0, plane_l + 0, NN);
    // --- layer 1 ---
    k_gemm_mfma<<<gemm_grid, 256, 0, stream>>>(plane_h, plane_l, BH, GH,
                                               wt1_h, wt1_l, nullptr, y, NN);
    k_aggregate<<<agg_blocks, 256, 0, stream>>>(y, off, csr_src, csr_w, b1,
                                                plane_h + GH, plane_l + GH, NN);
    // --- layer 2 ---
    k_gemm_mfma<<<gemm_grid, 256, 0, stream>>>(plane_h + GH, plane_l + GH, BH, GH,
                                               wt2_h, wt2_l, nullptr, y, NN);
    k_aggregate<<<agg_blocks, 256, 0, stream>>>(y, off, csr_src, csr_w, b2,
                                                plane_h + 2 * GH, plane_l + 2 * GH, NN);
    // --- readout: relu(cat)=cat, GEMM + bias ---
    k_gemm_mfma<<<gemm_grid, 256, 0, stream>>>(plane_h, plane_l, BH, BH,
                                               wtr_h, wtr_l, br, out, NN);
}

// Round 10
// 455.736 us; speedup vs baseline: 1.0306x; 1.0306x over previous
//
#include <hip/hip_runtime.h>

#define NN 20000
#define NE 320000
#define BH 768
#define GH 256

typedef __attribute__((ext_vector_type(8))) short short8;
typedef __attribute__((ext_vector_type(4))) float f32x4;

// ---------------- bf16 helpers (RNE) ----------------
__device__ __forceinline__ ushort f2bf(float x) {
    union { float f; unsigned u; } v; v.f = x;
    unsigned r = (v.u + 0x7FFFu + ((v.u >> 16) & 1u)) >> 16;
    return (ushort)r;
}
__device__ __forceinline__ float bf2f(ushort h) {
    union { unsigned u; float f; } v; v.u = ((unsigned)h) << 16;
    return v.f;
}

__device__ __forceinline__ void gload_lds16(const void* g, void* l) {
    __builtin_amdgcn_global_load_lds(
        (const __attribute__((address_space(1))) void*)g,
        (__attribute__((address_space(3))) void*)l, 16, 0, 0);
}

// ---------------- CSR build ----------------

__global__ void k_count(const int* __restrict__ dst, int* __restrict__ cnt, int E) {
    int i = blockIdx.x * blockDim.x + threadIdx.x;
    if (i < E) atomicAdd(&cnt[dst[i]], 1);
}

// chunked single-block scan: 1024 threads x 20 contiguous elements each.
__global__ __launch_bounds__(1024)
void k_scan(const int* __restrict__ cnt, int* __restrict__ off,
            int* __restrict__ fill, int n) {
    __shared__ int sbuf[1024];
    const int tid  = threadIdx.x;
    const int base = tid * 20;
    int local[20];
    int s = 0;
    #pragma unroll
    for (int i = 0; i < 20; ++i) {
        const int idx = base + i;
        int v = (idx < n) ? cnt[idx] : 0;
        local[i] = s;            // exclusive-within-chunk
        s += v;
    }
    sbuf[tid] = s;
    __syncthreads();
    int sum = s;
    for (int ofs = 1; ofs < 1024; ofs <<= 1) {
        int other = (tid >= ofs) ? sbuf[tid - ofs] : 0;
        __syncthreads();
        sum += other;
        sbuf[tid] = sum;
        __syncthreads();
    }
    const int excl = sum - s;    // exclusive prefix of this chunk
    #pragma unroll
    for (int i = 0; i < 20; ++i) {
        const int idx = base + i;
        if (idx < n) { const int v = excl + local[i]; off[idx] = v; fill[idx] = v; }
    }
    if (tid == 1023) off[n] = sum;
}

__global__ void k_scatter(const int* __restrict__ src, const int* __restrict__ dst,
                          const float* __restrict__ w, int* __restrict__ fill,
                          int* __restrict__ csr_src, float* __restrict__ csr_w, int E) {
    int i = blockIdx.x * blockDim.x + threadIdx.x;
    if (i < E) {
        int d = dst[i];
        int p = atomicAdd(&fill[d], 1);
        csr_src[p] = src[i];
        csr_w[p]  = w[i];
    }
}

// ---------------- fp32 -> bf16 hi/lo split (elementwise, float4) ----------------

__global__ void k_split(const float* __restrict__ x, ushort* __restrict__ hi,
                        ushort* __restrict__ lo, int n4) {
    int i = blockIdx.x * blockDim.x + threadIdx.x;
    if (i >= n4) return;
    float4 v = ((const float4*)x)[i];
    ushort4 h, l;
    h.x = f2bf(v.x); l.x = f2bf(v.x - bf2f(h.x));
    h.y = f2bf(v.y); l.y = f2bf(v.y - bf2f(h.y));
    h.z = f2bf(v.z); l.z = f2bf(v.z - bf2f(h.z));
    h.w = f2bf(v.w); l.w = f2bf(v.w - bf2f(h.w));
    ((ushort4*)hi)[i] = h;
    ((ushort4*)lo)[i] = l;
}

// W[K][N] row-major -> hi/lo planes transposed to [N][K]
__global__ void k_splitw(const float* __restrict__ W, ushort* __restrict__ hi,
                         ushort* __restrict__ lo, int K, int N) {
    int id = blockIdx.x * blockDim.x + threadIdx.x;
    if (id >= K * N) return;
    int n = id / K, k = id % K;
    float v = W[(size_t)k * N + n];
    ushort h = f2bf(v);
    hi[id] = h;
    lo[id] = f2bf(v - bf2f(h));
}

// ---------------- bf16x3 MFMA GEMM, double-buffered ----------------
// C[M x 256] = (Ah+Al)[M x K] * (Bh+Bl)^T  where B planes are stored [256][K].
// BM=64, BN=128, BK=32; 256 threads = 4 waves (2m x 2n), wave-tile 32x64.
// Round-9 lesson: occupancy alone didn't move MfmaUtil (17%) — the 2-barrier
// step serializes load latency. This version: double-buffered LDS, ONE barrier
// per step; prefetch of tile t+1 issues right after the barrier and its
// latency hides under ds_read+MFMA of tile t (the next __syncthreads' implicit
// vmcnt(0) is exactly the wait for t+1). BN=128 restores the L3-absorbed
// A-panel re-read (round-5 FETCH 61.6MB vs round-9 BN=64 127MB).
// LDS [rows][32] bf16, slot-swizzled: phys_slot = slot ^ ((row>>1)&3),
// applied on the global source (gload_lds dst stays linear), undone on read.

__global__ __launch_bounds__(256)
void k_gemm_mfma(const ushort* __restrict__ Ah, const ushort* __restrict__ Al,
                 int lda, int K,
                 const ushort* __restrict__ Bh, const ushort* __restrict__ Bl,
                 const float* __restrict__ bias,
                 float* __restrict__ C, int M) {
    __shared__ ushort As_h[2][64 * 32];
    __shared__ ushort As_l[2][64 * 32];
    __shared__ ushort Bs_h[2][128 * 32];
    __shared__ ushort Bs_l[2][128 * 32];

    const int t    = threadIdx.x;
    const int lane = t & 63;
    const int m0   = blockIdx.y * 64;
    const int n0   = blockIdx.x * 128;

    // A staging: 64 rows x 4 slots = 256 chunks of 16B, one per thread/plane
    const int ra = t >> 2;
    const int sa = (t & 3) ^ ((ra >> 1) & 3);
    int rga = m0 + ra; if (rga > M - 1) rga = M - 1;
    const size_t aofs = (size_t)rga * lda + (size_t)(sa * 8);
    // B staging: 128 rows x 4 slots = 512 chunks, two per thread/plane
    const int cb1 = t + 256;
    const int rb0 = t >> 2,   rb1 = cb1 >> 2;
    const int sb0 = (t & 3)   ^ ((rb0 >> 1) & 3);
    const int sb1 = (cb1 & 3) ^ ((rb1 >> 1) & 3);
    const size_t bofs0 = (size_t)(n0 + rb0) * K + (size_t)(sb0 * 8);
    const size_t bofs1 = (size_t)(n0 + rb1) * K + (size_t)(sb1 * 8);
    const int d0 = (t >> 6) << 10;      // wave-contiguous 1KB LDS region
    const int d1 = (cb1 >> 6) << 10;    // second B chunk region (4KB..8KB)

    const int wm = (t >> 6) & 1;
    const int wn = t >> 7;

    f32x4 zero = (f32x4)0.0f;
    f32x4 acc[2][4];
    #pragma unroll
    for (int i = 0; i < 2; ++i)
        #pragma unroll
        for (int j = 0; j < 4; ++j) acc[i][j] = zero;

    const int fr  = lane & 15;
    const int fsl = lane >> 4;

    auto STAGE = [&](int buf, int k0) {
        gload_lds16(Ah + aofs + k0, (char*)As_h[buf] + d0);
        gload_lds16(Al + aofs + k0, (char*)As_l[buf] + d0);
        gload_lds16(Bh + bofs0 + k0, (char*)Bs_h[buf] + d0);
        gload_lds16(Bh + bofs1 + k0, (char*)Bs_h[buf] + d1);
        gload_lds16(Bl + bofs0 + k0, (char*)Bs_l[buf] + d0);
        gload_lds16(Bl + bofs1 + k0, (char*)Bs_l[buf] + d1);
    };

    STAGE(0, 0);                 // prologue prefetch into buffer 0
    int cur = 0;
    for (int k0 = 0; k0 < K; k0 += 32, cur ^= 1) {
        __syncthreads();         // drains vmcnt(0): buf[cur] is ready
        if (k0 + 32 < K) STAGE(cur ^ 1, k0 + 32);   // prefetch next tile

        short8 ah[2], al2[2], bh[4], bl[4];
        #pragma unroll
        for (int i = 0; i < 2; ++i) {
            const int r = wm * 32 + i * 16 + fr;
            const int s = fsl ^ ((r >> 1) & 3);
            ah[i]  = *(const short8*)(&As_h[cur][0] + r * 32 + s * 8);
            al2[i] = *(const short8*)(&As_l[cur][0] + r * 32 + s * 8);
        }
        #pragma unroll
        for (int j = 0; j < 4; ++j) {
            const int r = wn * 64 + j * 16 + fr;
            const int s = fsl ^ ((r >> 1) & 3);
            bh[j] = *(const short8*)(&Bs_h[cur][0] + r * 32 + s * 8);
            bl[j] = *(const short8*)(&Bs_l[cur][0] + r * 32 + s * 8);
        }
        #pragma unroll
        for (int i = 0; i < 2; ++i)
            #pragma unroll
            for (int j = 0; j < 4; ++j) {
                acc[i][j] = __builtin_amdgcn_mfma_f32_16x16x32_bf16(ah[i],  bh[j], acc[i][j], 0, 0, 0);
                acc[i][j] = __builtin_amdgcn_mfma_f32_16x16x32_bf16(ah[i],  bl[j], acc[i][j], 0, 0, 0);
                acc[i][j] = __builtin_amdgcn_mfma_f32_16x16x32_bf16(al2[i], bh[j], acc[i][j], 0, 0, 0);
            }
    }

    // epilogue: C/D layout col = lane&15, row = (lane>>4)*4 + reg
    #pragma unroll
    for (int i = 0; i < 2; ++i) {
        #pragma unroll
        for (int j = 0; j < 4; ++j) {
            const int col = n0 + wn * 64 + j * 16 + fr;
            const int r0  = m0 + wm * 32 + i * 16 + ((lane >> 4) << 2);
            const float ba = bias ? bias[col] : 0.0f;
            #pragma unroll
            for (int q = 0; q < 4; ++q) {
                const int r = r0 + q;
                if (r < M) C[(size_t)r * 256 + col] = acc[i][j][q] + ba;
            }
        }
    }
}

// ---------------- edge aggregation + bias + relu -> bf16 hi/lo concat planes --------
// one wave per node; lane owns 4 contiguous floats of the 256-dim feature.
// 4-way edge unroll: 4 independent accumulators -> 4 gathers in flight per wave.

__global__ __launch_bounds__(256)
void k_aggregate(const float* __restrict__ y,
                 const int* __restrict__ off,
                 const int* __restrict__ csr_src,
                 const float* __restrict__ csr_w,
                 const float* __restrict__ bias,
                 ushort* __restrict__ cat_h,   // plane + layer*256; row stride 768
                 ushort* __restrict__ cat_l,
                 int n) {
    const int wave = blockIdx.x * (blockDim.x >> 6) + (threadIdx.x >> 6);
    const int lane = threadIdx.x & 63;
    if (wave >= n) return;
    const int c = lane * 4;

    // independent (hoisted) loads: overlap with the edge loop
    float4 self = *(const float4*)(y + (size_t)wave * GH + c);
    float4 b    = *(const float4*)(bias + c);

    float4 a0 = make_float4(0.f, 0.f, 0.f, 0.f);
    float4 a1 = a0, a2 = a0, a3 = a0;
    const int e0 = off[wave], e1 = off[wave + 1];
    int e = e0;
    for (; e + 4 <= e1; e += 4) {
        const int   s0 = csr_src[e],     s1 = csr_src[e + 1];
        const int   s2 = csr_src[e + 2], s3 = csr_src[e + 3];
        const float w0 = csr_w[e],       w1 = csr_w[e + 1];
        const float w2 = csr_w[e + 2],   w3 = csr_w[e + 3];
        float4 v0 = *(const float4*)(y + (size_t)s0 * GH + c);
        float4 v1 = *(const float4*)(y + (size_t)s1 * GH + c);
        float4 v2 = *(const float4*)(y + (size_t)s2 * GH + c);
        float4 v3 = *(const float4*)(y + (size_t)s3 * GH + c);
        a0.x = fmaf(w0, v0.x, a0.x); a0.y = fmaf(w0, v0.y, a0.y);
        a0.z = fmaf(w0, v0.z, a0.z); a0.w = fmaf(w0, v0.w, a0.w);
        a1.x = fmaf(w1, v1.x, a1.x); a1.y = fmaf(w1, v1.y, a1.y);
        a1.z = fmaf(w1, v1.z, a1.z); a1.w = fmaf(w1, v1.w, a1.w);
        a2.x = fmaf(w2, v2.x, a2.x); a2.y = fmaf(w2, v2.y, a2.y);
        a2.z = fmaf(w2, v2.z, a2.z); a2.w = fmaf(w2, v2.w, a2.w);
        a3.x = fmaf(w3, v3.x, a3.x); a3.y = fmaf(w3, v3.y, a3.y);
        a3.z = fmaf(w3, v3.z, a3.z); a3.w = fmaf(w3, v3.w, a3.w);
    }
    for (; e < e1; ++e) {
        const int   s = csr_src[e];
        const float w = csr_w[e];
        float4 v = *(const float4*)(y + (size_t)s * GH + c);
        a0.x = fmaf(w, v.x, a0.x); a0.y = fmaf(w, v.y, a0.y);
        a0.z = fmaf(w, v.z, a0.z); a0.w = fmaf(w, v.w, a0.w);
    }
    float4 r;
    r.x = fmaxf(self.x + ((a0.x + a1.x) + (a2.x + a3.x)) + b.x, 0.f);
    r.y = fmaxf(self.y + ((a0.y + a1.y) + (a2.y + a3.y)) + b.y, 0.f);
    r.z = fmaxf(self.z + ((a0.z + a1.z) + (a2.z + a3.z)) + b.z, 0.f);
    r.w = fmaxf(self.w + ((a0.w + a1.w) + (a2.w + a3.w)) + b.w, 0.f);
    ushort4 h, l;
    h.x = f2bf(r.x); l.x = f2bf(r.x - bf2f(h.x));
    h.y = f2bf(r.y); l.y = f2bf(r.y - bf2f(h.y));
    h.z = f2bf(r.z); l.z = f2bf(r.z - bf2f(h.z));
    h.w = f2bf(r.w); l.w = f2bf(r.w - bf2f(h.w));
    *(ushort4*)(cat_h + (size_t)wave * BH + c) = h;
    *(ushort4*)(cat_l + (size_t)wave * BH + c) = l;
}

// ---------------- launcher ----------------

extern "C" void kernel_launch(void* const* d_in, const int* in_sizes, int n_in,
                              void* d_out, int out_size, void* d_ws, size_t ws_size,
                              hipStream_t stream) {
    const float* node_embed = (const float*)d_in[0];
    const float* edge_w     = (const float*)d_in[1];
    const float* W0 = (const float*)d_in[2];
    const float* b0 = (const float*)d_in[3];
    const float* W1 = (const float*)d_in[4];
    const float* b1 = (const float*)d_in[5];
    const float* W2 = (const float*)d_in[6];
    const float* b2 = (const float*)d_in[7];
    const float* Wr = (const float*)d_in[8];
    const float* br = (const float*)d_in[9];
    const int* src  = (const int*)d_in[10];
    const int* dst  = (const int*)d_in[11];
    float* out = (float*)d_out;

    char* p = (char*)d_ws;
    auto carve = [&](size_t bytes) {
        void* r = (void*)p;
        p += (bytes + 255) & ~(size_t)255;
        return r;
    };
    ushort* plane_h = (ushort*)carve((size_t)NN * BH * 2);   // 30.72 MB
    ushort* plane_l = (ushort*)carve((size_t)NN * BH * 2);   // 30.72 MB
    float*  y       = (float*) carve((size_t)NN * GH * 4);   // 20.48 MB
    ushort* wt0_h = (ushort*)carve((size_t)GH * BH * 2);
    ushort* wt0_l = (ushort*)carve((size_t)GH * BH * 2);
    ushort* wt1_h = (ushort*)carve((size_t)GH * GH * 2);
    ushort* wt1_l = (ushort*)carve((size_t)GH * GH * 2);
    ushort* wt2_h = (ushort*)carve((size_t)GH * GH * 2);
    ushort* wt2_l = (ushort*)carve((size_t)GH * GH * 2);
    ushort* wtr_h = (ushort*)carve((size_t)GH * BH * 2);
    ushort* wtr_l = (ushort*)carve((size_t)GH * BH * 2);
    int*    cnt     = (int*)  carve((size_t)NN * 4);
    int*    off     = (int*)  carve((size_t)(NN + 1) * 4);
    int*    fill    = (int*)  carve((size_t)NN * 4);
    int*    csr_src = (int*)  carve((size_t)NE * 4);
    float*  csr_w   = (float*)carve((size_t)NE * 4);
    (void)ws_size; (void)n_in; (void)in_sizes; (void)out_size;

    // --- CSR build ---
    hipMemsetAsync(cnt, 0, (size_t)NN * 4, stream);
    k_count<<<(NE + 255) / 256, 256, 0, stream>>>(dst, cnt, NE);
    k_scan<<<1, 1024, 0, stream>>>(cnt, off, fill, NN);
    k_scatter<<<(NE + 255) / 256, 256, 0, stream>>>(src, dst, edge_w, fill,
                                                    csr_src, csr_w, NE);

    // --- precision splits ---
    const int n4 = NN * BH / 4;
    k_split<<<(n4 + 255) / 256, 256, 0, stream>>>(node_embed, plane_h, plane_l, n4);
    k_splitw<<<(BH * GH + 255) / 256, 256, 0, stream>>>(W0, wt0_h, wt0_l, BH, GH);
    k_splitw<<<(GH * GH + 255) / 256, 256, 0, stream>>>(W1, wt1_h, wt1_l, GH, GH);
    k_splitw<<<(GH * GH + 255) / 256, 256, 0, stream>>>(W2, wt2_h, wt2_l, GH, GH);
    k_splitw<<<(BH * GH + 255) / 256, 256, 0, stream>>>(Wr, wtr_h, wtr_l, BH, GH);

    dim3 gemm_grid(2, (NN + 63) / 64);          // (2, 313) = 626 blocks
    const int agg_blocks = (NN + 3) / 4;        // 4 waves/block, 1 node/wave

    // --- layer 0: project first (768->256), then aggregate in 256-dim ---
    k_gemm_mfma<<<gemm_grid, 256, 0, stream>>>(plane_h, plane_l, BH, BH,
                                               wt0_h, wt0_l, nullptr, y, NN);
    k_aggregate<<<agg_blocks, 256, 0, stream>>>(y, off, csr_src, csr_w, b0,
                                                plane_h + 0, plane_l + 0, NN);
    // --- layer 1 ---
    k_gemm_mfma<<<gemm_grid, 256, 0, stream>>>(plane_h, plane_l, BH, GH,
                                               wt1_h, wt1_l, nullptr, y, NN);
    k_aggregate<<<agg_blocks, 256, 0, stream>>>(y, off, csr_src, csr_w, b1,
                                                plane_h + GH, plane_l + GH, NN);
    // --- layer 2 ---
    k_gemm_mfma<<<gemm_grid, 256, 0, stream>>>(plane_h + GH, plane_l + GH, BH, GH,
                                               wt2_h, wt2_l, nullptr, y, NN);
    k_aggregate<<<agg_blocks, 256, 0, stream>>>(y, off, csr_src, csr_w, b2,
                                                plane_h + 2 * GH, plane_l + 2 * GH, NN);
    // --- readout: relu(cat)=cat, GEMM + bias ---
    k_gemm_mfma<<<gemm_grid, 256, 0, stream>>>(plane_h, plane_l, BH, BH,
                                               wtr_h, wtr_l, br, out, NN);
}

// Round 12
// 403.706 us; speedup vs baseline: 1.1634x; 1.1289x over previous
//
#include <hip/hip_runtime.h>

#define NN 20000
#define NE 320000
#define BH 768
#define GH 256

typedef __attribute__((ext_vector_type(8))) short short8;
typedef __attribute__((ext_vector_type(4))) float f32x4;

// ---------------- bf16 helpers (RNE) ----------------
__device__ __forceinline__ ushort f2bf(float x) {
    union { float f; unsigned u; } v; v.f = x;
    unsigned r = (v.u + 0x7FFFu + ((v.u >> 16) & 1u)) >> 16;
    return (ushort)r;
}
__device__ __forceinline__ float bf2f(ushort h) {
    union { unsigned u; float f; } v; v.u = ((unsigned)h) << 16;
    return v.f;
}
// ---------------- fp16 helpers (RNE via v_cvt) ----------------
__device__ __forceinline__ ushort f2h(float x) {
    union { _Float16 h; ushort u; } v; v.h = (_Float16)x; return v.u;
}
__device__ __forceinline__ float h2f(ushort u) {
    union { _Float16 h; ushort u; } v; v.u = u; return (float)v.h;
}

__device__ __forceinline__ void gload_lds16(const void* g, void* l) {
    __builtin_amdgcn_global_load_lds(
        (const __attribute__((address_space(1))) void*)g,
        (__attribute__((address_space(3))) void*)l, 16, 0, 0);
}

// ---------------- CSR build ----------------

__global__ void k_count(const int* __restrict__ dst, int* __restrict__ cnt, int E) {
    int i = blockIdx.x * blockDim.x + threadIdx.x;
    if (i < E) atomicAdd(&cnt[dst[i]], 1);
}

// chunked single-block scan: 1024 threads x 20 contiguous elements each.
__global__ __launch_bounds__(1024)
void k_scan(const int* __restrict__ cnt, int* __restrict__ off,
            int* __restrict__ fill, int n) {
    __shared__ int sbuf[1024];
    const int tid  = threadIdx.x;
    const int base = tid * 20;
    int local[20];
    int s = 0;
    #pragma unroll
    for (int i = 0; i < 20; ++i) {
        const int idx = base + i;
        int v = (idx < n) ? cnt[idx] : 0;
        local[i] = s;            // exclusive-within-chunk
        s += v;
    }
    sbuf[tid] = s;
    __syncthreads();
    int sum = s;
    for (int ofs = 1; ofs < 1024; ofs <<= 1) {
        int other = (tid >= ofs) ? sbuf[tid - ofs] : 0;
        __syncthreads();
        sum += other;
        sbuf[tid] = sum;
        __syncthreads();
    }
    const int excl = sum - s;    // exclusive prefix of this chunk
    #pragma unroll
    for (int i = 0; i < 20; ++i) {
        const int idx = base + i;
        if (idx < n) { const int v = excl + local[i]; off[idx] = v; fill[idx] = v; }
    }
    if (tid == 1023) off[n] = sum;
}

__global__ void k_scatter(const int* __restrict__ src, const int* __restrict__ dst,
                          const float* __restrict__ w, int* __restrict__ fill,
                          int* __restrict__ csr_src, float* __restrict__ csr_w, int E) {
    int i = blockIdx.x * blockDim.x + threadIdx.x;
    if (i < E) {
        int d = dst[i];
        int p = atomicAdd(&fill[d], 1);
        csr_src[p] = src[i];
        csr_w[p]  = w[i];
    }
}

// ---------------- fp32 -> bf16 hi/lo split (elementwise, float4) ----------------

__global__ void k_split(const float* __restrict__ x, ushort* __restrict__ hi,
                        ushort* __restrict__ lo, int n4) {
    int i = blockIdx.x * blockDim.x + threadIdx.x;
    if (i >= n4) return;
    float4 v = ((const float4*)x)[i];
    ushort4 h, l;
    h.x = f2bf(v.x); l.x = f2bf(v.x - bf2f(h.x));
    h.y = f2bf(v.y); l.y = f2bf(v.y - bf2f(h.y));
    h.z = f2bf(v.z); l.z = f2bf(v.z - bf2f(h.z));
    h.w = f2bf(v.w); l.w = f2bf(v.w - bf2f(h.w));
    ((ushort4*)hi)[i] = h;
    ((ushort4*)lo)[i] = l;
}

// W[K][N] row-major -> hi/lo planes transposed to [N][K]
__global__ void k_splitw(const float* __restrict__ W, ushort* __restrict__ hi,
                         ushort* __restrict__ lo, int K, int N) {
    int id = blockIdx.x * blockDim.x + threadIdx.x;
    if (id >= K * N) return;
    int n = id / K, k = id % K;
    float v = W[(size_t)k * N + n];
    ushort h = f2bf(v);
    hi[id] = h;
    lo[id] = f2bf(v - bf2f(h));
}

// ---------------- bf16x3 MFMA GEMM, double-buffered ----------------
// C[M x 256] = (Ah+Al)[M x K] * (Bh+Bl)^T  where B planes are stored [256][K].
// BM=64, BN=128, BK=32; 256 threads = 4 waves (2m x 2n), wave-tile 32x64.
// Double-buffered LDS, ONE barrier per step (round-10: dropped GEMMs below agg).
// Optionally also writes C as fp16 (Ch) for the fp16 neighbor-gather path.
// LDS [rows][32] bf16, slot-swizzled: phys_slot = slot ^ ((row>>1)&3),
// applied on the global source (gload_lds dst stays linear), undone on read.

__global__ __launch_bounds__(256)
void k_gemm_mfma(const ushort* __restrict__ Ah, const ushort* __restrict__ Al,
                 int lda, int K,
                 const ushort* __restrict__ Bh, const ushort* __restrict__ Bl,
                 const float* __restrict__ bias,
                 float* __restrict__ C, ushort* __restrict__ Ch, int M) {
    __shared__ ushort As_h[2][64 * 32];
    __shared__ ushort As_l[2][64 * 32];
    __shared__ ushort Bs_h[2][128 * 32];
    __shared__ ushort Bs_l[2][128 * 32];

    const int t    = threadIdx.x;
    const int lane = t & 63;
    const int m0   = blockIdx.y * 64;
    const int n0   = blockIdx.x * 128;

    // A staging: 64 rows x 4 slots = 256 chunks of 16B, one per thread/plane
    const int ra = t >> 2;
    const int sa = (t & 3) ^ ((ra >> 1) & 3);
    int rga = m0 + ra; if (rga > M - 1) rga = M - 1;
    const size_t aofs = (size_t)rga * lda + (size_t)(sa * 8);
    // B staging: 128 rows x 4 slots = 512 chunks, two per thread/plane
    const int cb1 = t + 256;
    const int rb0 = t >> 2,   rb1 = cb1 >> 2;
    const int sb0 = (t & 3)   ^ ((rb0 >> 1) & 3);
    const int sb1 = (cb1 & 3) ^ ((rb1 >> 1) & 3);
    const size_t bofs0 = (size_t)(n0 + rb0) * K + (size_t)(sb0 * 8);
    const size_t bofs1 = (size_t)(n0 + rb1) * K + (size_t)(sb1 * 8);
    const int d0 = (t >> 6) << 10;      // wave-contiguous 1KB LDS region
    const int d1 = (cb1 >> 6) << 10;    // second B chunk region (4KB..8KB)

    const int wm = (t >> 6) & 1;
    const int wn = t >> 7;

    f32x4 zero = (f32x4)0.0f;
    f32x4 acc[2][4];
    #pragma unroll
    for (int i = 0; i < 2; ++i)
        #pragma unroll
        for (int j = 0; j < 4; ++j) acc[i][j] = zero;

    const int fr  = lane & 15;
    const int fsl = lane >> 4;

    auto STAGE = [&](int buf, int k0) {
        gload_lds16(Ah + aofs + k0, (char*)As_h[buf] + d0);
        gload_lds16(Al + aofs + k0, (char*)As_l[buf] + d0);
        gload_lds16(Bh + bofs0 + k0, (char*)Bs_h[buf] + d0);
        gload_lds16(Bh + bofs1 + k0, (char*)Bs_h[buf] + d1);
        gload_lds16(Bl + bofs0 + k0, (char*)Bs_l[buf] + d0);
        gload_lds16(Bl + bofs1 + k0, (char*)Bs_l[buf] + d1);
    };

    STAGE(0, 0);                 // prologue prefetch into buffer 0
    int cur = 0;
    for (int k0 = 0; k0 < K; k0 += 32, cur ^= 1) {
        __syncthreads();         // drains vmcnt(0): buf[cur] is ready
        if (k0 + 32 < K) STAGE(cur ^ 1, k0 + 32);   // prefetch next tile

        short8 ah[2], al2[2], bh[4], bl[4];
        #pragma unroll
        for (int i = 0; i < 2; ++i) {
            const int r = wm * 32 + i * 16 + fr;
            const int s = fsl ^ ((r >> 1) & 3);
            ah[i]  = *(const short8*)(&As_h[cur][0] + r * 32 + s * 8);
            al2[i] = *(const short8*)(&As_l[cur][0] + r * 32 + s * 8);
        }
        #pragma unroll
        for (int j = 0; j < 4; ++j) {
            const int r = wn * 64 + j * 16 + fr;
            const int s = fsl ^ ((r >> 1) & 3);
            bh[j] = *(const short8*)(&Bs_h[cur][0] + r * 32 + s * 8);
            bl[j] = *(const short8*)(&Bs_l[cur][0] + r * 32 + s * 8);
        }
        #pragma unroll
        for (int i = 0; i < 2; ++i)
            #pragma unroll
            for (int j = 0; j < 4; ++j) {
                acc[i][j] = __builtin_amdgcn_mfma_f32_16x16x32_bf16(ah[i],  bh[j], acc[i][j], 0, 0, 0);
                acc[i][j] = __builtin_amdgcn_mfma_f32_16x16x32_bf16(ah[i],  bl[j], acc[i][j], 0, 0, 0);
                acc[i][j] = __builtin_amdgcn_mfma_f32_16x16x32_bf16(al2[i], bh[j], acc[i][j], 0, 0, 0);
            }
    }

    // epilogue: C/D layout col = lane&15, row = (lane>>4)*4 + reg
    #pragma unroll
    for (int i = 0; i < 2; ++i) {
        #pragma unroll
        for (int j = 0; j < 4; ++j) {
            const int col = n0 + wn * 64 + j * 16 + fr;
            const int r0  = m0 + wm * 32 + i * 16 + ((lane >> 4) << 2);
            const float ba = bias ? bias[col] : 0.0f;
            #pragma unroll
            for (int q = 0; q < 4; ++q) {
                const int r = r0 + q;
                if (r < M) {
                    const float v = acc[i][j][q] + ba;
                    C[(size_t)r * 256 + col] = v;
                    if (Ch) Ch[(size_t)r * 256 + col] = f2h(v);
                }
            }
        }
    }
}

// ---------------- edge aggregation + bias + relu -> bf16 hi/lo concat planes --------
// one wave per node; lane owns 4 contiguous floats of the 256-dim feature.
// Neighbors gathered from the fp16 plane (8B/lane: halves L3 traffic AND working
// set 20.5->10.2 MB for better per-XCD L2 hit rate); self + bias stay fp32.
// 4-way edge unroll: 4 independent accumulators -> 4 gathers in flight per wave.

__global__ __launch_bounds__(256)
void k_aggregate(const float* __restrict__ y,
                 const ushort* __restrict__ yh,   // fp16 copy of y
                 const int* __restrict__ off,
                 const int* __restrict__ csr_src,
                 const float* __restrict__ csr_w,
                 const float* __restrict__ bias,
                 ushort* __restrict__ cat_h,   // plane + layer*256; row stride 768
                 ushort* __restrict__ cat_l,
                 int n) {
    const int wave = blockIdx.x * (blockDim.x >> 6) + (threadIdx.x >> 6);
    const int lane = threadIdx.x & 63;
    if (wave >= n) return;
    const int c = lane * 4;

    // independent (hoisted) loads: overlap with the edge loop
    float4 self = *(const float4*)(y + (size_t)wave * GH + c);
    float4 b    = *(const float4*)(bias + c);

    float4 a0 = make_float4(0.f, 0.f, 0.f, 0.f);
    float4 a1 = a0, a2 = a0, a3 = a0;
    const int e0 = off[wave], e1 = off[wave + 1];
    int e = e0;
    for (; e + 4 <= e1; e += 4) {
        const int   s0 = csr_src[e],     s1 = csr_src[e + 1];
        const int   s2 = csr_src[e + 2], s3 = csr_src[e + 3];
        const float w0 = csr_w[e],       w1 = csr_w[e + 1];
        const float w2 = csr_w[e + 2],   w3 = csr_w[e + 3];
        ushort4 v0 = *(const ushort4*)(yh + (size_t)s0 * GH + c);
        ushort4 v1 = *(const ushort4*)(yh + (size_t)s1 * GH + c);
        ushort4 v2 = *(const ushort4*)(yh + (size_t)s2 * GH + c);
        ushort4 v3 = *(const ushort4*)(yh + (size_t)s3 * GH + c);
        a0.x = fmaf(w0, h2f(v0.x), a0.x); a0.y = fmaf(w0, h2f(v0.y), a0.y);
        a0.z = fmaf(w0, h2f(v0.z), a0.z); a0.w = fmaf(w0, h2f(v0.w), a0.w);
        a1.x = fmaf(w1, h2f(v1.x), a1.x); a1.y = fmaf(w1, h2f(v1.y), a1.y);
        a1.z = fmaf(w1, h2f(v1.z), a1.z); a1.w = fmaf(w1, h2f(v1.w), a1.w);
        a2.x = fmaf(w2, h2f(v2.x), a2.x); a2.y = fmaf(w2, h2f(v2.y), a2.y);
        a2.z = fmaf(w2, h2f(v2.z), a2.z); a2.w = fmaf(w2, h2f(v2.w), a2.w);
        a3.x = fmaf(w3, h2f(v3.x), a3.x); a3.y = fmaf(w3, h2f(v3.y), a3.y);
        a3.z = fmaf(w3, h2f(v3.z), a3.z); a3.w = fmaf(w3, h2f(v3.w), a3.w);
    }
    for (; e < e1; ++e) {
        const int   s = csr_src[e];
        const float w = csr_w[e];
        ushort4 v = *(const ushort4*)(yh + (size_t)s * GH + c);
        a0.x = fmaf(w, h2f(v.x), a0.x); a0.y = fmaf(w, h2f(v.y), a0.y);
        a0.z = fmaf(w, h2f(v.z), a0.z); a0.w = fmaf(w, h2f(v.w), a0.w);
    }
    float4 r;
    r.x = fmaxf(self.x + ((a0.x + a1.x) + (a2.x + a3.x)) + b.x, 0.f);
    r.y = fmaxf(self.y + ((a0.y + a1.y) + (a2.y + a3.y)) + b.y, 0.f);
    r.z = fmaxf(self.z + ((a0.z + a1.z) + (a2.z + a3.z)) + b.z, 0.f);
    r.w = fmaxf(self.w + ((a0.w + a1.w) + (a2.w + a3.w)) + b.w, 0.f);
    ushort4 h, l;
    h.x = f2bf(r.x); l.x = f2bf(r.x - bf2f(h.x));
    h.y = f2bf(r.y); l.y = f2bf(r.y - bf2f(h.y));
    h.z = f2bf(r.z); l.z = f2bf(r.z - bf2f(h.z));
    h.w = f2bf(r.w); l.w = f2bf(r.w - bf2f(h.w));
    *(ushort4*)(cat_h + (size_t)wave * BH + c) = h;
    *(ushort4*)(cat_l + (size_t)wave * BH + c) = l;
}

// ---------------- launcher ----------------

extern "C" void kernel_launch(void* const* d_in, const int* in_sizes, int n_in,
                              void* d_out, int out_size, void* d_ws, size_t ws_size,
                              hipStream_t stream) {
    const float* node_embed = (const float*)d_in[0];
    const float* edge_w     = (const float*)d_in[1];
    const float* W0 = (const float*)d_in[2];
    const float* b0 = (const float*)d_in[3];
    const float* W1 = (const float*)d_in[4];
    const float* b1 = (const float*)d_in[5];
    const float* W2 = (const float*)d_in[6];
    const float* b2 = (const float*)d_in[7];
    const float* Wr = (const float*)d_in[8];
    const float* br = (const float*)d_in[9];
    const int* src  = (const int*)d_in[10];
    const int* dst  = (const int*)d_in[11];
    float* out = (float*)d_out;

    char* p = (char*)d_ws;
    auto carve = [&](size_t bytes) {
        void* r = (void*)p;
        p += (bytes + 255) & ~(size_t)255;
        return r;
    };
    ushort* plane_h = (ushort*)carve((size_t)NN * BH * 2);   // 30.72 MB
    ushort* plane_l = (ushort*)carve((size_t)NN * BH * 2);   // 30.72 MB
    float*  y       = (float*) carve((size_t)NN * GH * 4);   // 20.48 MB
    ushort* yh      = (ushort*)carve((size_t)NN * GH * 2);   // 10.24 MB fp16
    ushort* wt0_h = (ushort*)carve((size_t)GH * BH * 2);
    ushort* wt0_l = (ushort*)carve((size_t)GH * BH * 2);
    ushort* wt1_h = (ushort*)carve((size_t)GH * GH * 2);
    ushort* wt1_l = (ushort*)carve((size_t)GH * GH * 2);
    ushort* wt2_h = (ushort*)carve((size_t)GH * GH * 2);
    ushort* wt2_l = (ushort*)carve((size_t)GH * GH * 2);
    ushort* wtr_h = (ushort*)carve((size_t)GH * BH * 2);
    ushort* wtr_l = (ushort*)carve((size_t)GH * BH * 2);
    int*    cnt     = (int*)  carve((size_t)NN * 4);
    int*    off     = (int*)  carve((size_t)(NN + 1) * 4);
    int*    fill    = (int*)  carve((size_t)NN * 4);
    int*    csr_src = (int*)  carve((size_t)NE * 4);
    float*  csr_w   = (float*)carve((size_t)NE * 4);
    (void)ws_size; (void)n_in; (void)in_sizes; (void)out_size;

    // --- CSR build ---
    hipMemsetAsync(cnt, 0, (size_t)NN * 4, stream);
    k_count<<<(NE + 255) / 256, 256, 0, stream>>>(dst, cnt, NE);
    k_scan<<<1, 1024, 0, stream>>>(cnt, off, fill, NN);
    k_scatter<<<(NE + 255) / 256, 256, 0, stream>>>(src, dst, edge_w, fill,
                                                    csr_src, csr_w, NE);

    // --- precision splits ---
    const int n4 = NN * BH / 4;
    k_split<<<(n4 + 255) / 256, 256, 0, stream>>>(node_embed, plane_h, plane_l, n4);
    k_splitw<<<(BH * GH + 255) / 256, 256, 0, stream>>>(W0, wt0_h, wt0_l, BH, GH);
    k_splitw<<<(GH * GH + 255) / 256, 256, 0, stream>>>(W1, wt1_h, wt1_l, GH, GH);
    k_splitw<<<(GH * GH + 255) / 256, 256, 0, stream>>>(W2, wt2_h, wt2_l, GH, GH);
    k_splitw<<<(BH * GH + 255) / 256, 256, 0, stream>>>(Wr, wtr_h, wtr_l, BH, GH);

    dim3 gemm_grid(2, (NN + 63) / 64);          // (2, 313) = 626 blocks
    const int agg_blocks = (NN + 3) / 4;        // 4 waves/block, 1 node/wave

    // --- layer 0: project first (768->256), then aggregate in 256-dim ---
    k_gemm_mfma<<<gemm_grid, 256, 0, stream>>>(plane_h, plane_l, BH, BH,
                                               wt0_h, wt0_l, nullptr, y, yh, NN);
    k_aggregate<<<agg_blocks, 256, 0, stream>>>(y, yh, off, csr_src, csr_w, b0,
                                                plane_h + 0, plane_l + 0, NN);
    // --- layer 1 ---
    k_gemm_mfma<<<gemm_grid, 256, 0, stream>>>(plane_h, plane_l, BH, GH,
                                               wt1_h, wt1_l, nullptr, y, yh, NN);
    k_aggregate<<<agg_blocks, 256, 0, stream>>>(y, yh, off, csr_src, csr_w, b1,
                                                plane_h + GH, plane_l + GH, NN);
    // --- layer 2 ---
    k_gemm_mfma<<<gemm_grid, 256, 0, stream>>>(plane_h + GH, plane_l + GH, BH, GH,
                                               wt2_h, wt2_l, nullptr, y, yh, NN);
    k_aggregate<<<agg_blocks, 256, 0, stream>>>(y, yh, off, csr_src, csr_w, b2,
                                                plane_h + 2 * GH, plane_l + 2 * GH, NN);
    // --- readout: relu(cat)=cat, GEMM + bias (no fp16 copy needed) ---
    k_gemm_mfma<<<gemm_grid, 256, 0, stream>>>(plane_h, plane_l, BH, BH,
                                               wtr_h, wtr_l, br, out, nullptr, NN);
}